// Round 1
// baseline (1836.048 us; speedup 1.0000x reference)
//
#include <hip/hip_runtime.h>
#include <math.h>

#define B_    2
#define C_    128
#define N_    2048
#define HID_  512
#define HEADS_ 8
#define EPS_  1e-6f
#define NS_   0.2f

// ---------------------------------------------------------------------------
// vec_layernorm: per (b,n): nrm_c = sqrt(sum_t x^2 + eps); mean/var over c;
// y = x / (nrm + eps) * ((nrm - mu) * rstd * gamma_c + beta_c)
// grid (N/32, B), block 256 (nn = tid&31, cg = tid>>5)
// ---------------------------------------------------------------------------
__global__ __launch_bounds__(256) void ln_kernel(const float* __restrict__ x,
        const float* __restrict__ gma, const float* __restrict__ bta,
        float* __restrict__ y)
{
    __shared__ float norms[128][32];
    __shared__ float red1[8][32];
    __shared__ float red2[8][32];
    const int b  = blockIdx.y;
    const int n0 = blockIdx.x * 32;
    const int nn = threadIdx.x & 31;
    const int cg = threadIdx.x >> 5;

    float s1 = 0.f, s2 = 0.f;
    for (int it = 0; it < 16; ++it) {
        int c = it * 8 + cg;
        size_t base = ((size_t)(b * C_ + c) * 3) * N_ + n0 + nn;
        float x0 = x[base], x1 = x[base + N_], x2 = x[base + 2 * N_];
        float nr = sqrtf(x0 * x0 + x1 * x1 + x2 * x2 + EPS_);
        norms[c][nn] = nr;
        s1 += nr; s2 += nr * nr;
    }
    red1[cg][nn] = s1; red2[cg][nn] = s2;
    __syncthreads();
    float S1 = 0.f, S2 = 0.f;
    #pragma unroll
    for (int g = 0; g < 8; ++g) { S1 += red1[g][nn]; S2 += red2[g][nn]; }
    float mu   = S1 * (1.f / 128.f);
    float var  = S2 * (1.f / 128.f) - mu * mu;
    float rstd = rsqrtf(var + EPS_);

    for (int it = 0; it < 16; ++it) {
        int c = it * 8 + cg;
        float nr = norms[c][nn];
        float ln = (nr - mu) * rstd * gma[c] + bta[c];
        float sc = ln / (nr + EPS_);
        size_t base = ((size_t)(b * C_ + c) * 3) * N_ + n0 + nn;
        y[base]          = x[base] * sc;
        y[base + N_]     = x[base + N_] * sc;
        y[base + 2 * N_] = x[base + 2 * N_] * sc;
    }
}

// ---------------------------------------------------------------------------
// GEMM: Y[b,o,m] = (Z?Z[b,o,m]:0) + sum_c W[o*wstride+c] * X(b,c,m)
// XMODE 0: X[(b*K+c)*M + m], M = 3*N_
// XMODE 1: m = t*N_+n, X[((b*N_+n)*3+t)*K + c]   (graph edge buffer, NT layout)
// grid (M/64, O/64, B), block 256, 64x64x16 tiles, 4x4 micro
// ---------------------------------------------------------------------------
template <int XMODE>
__global__ __launch_bounds__(256) void gemm_kernel(
    const float* __restrict__ W, int wstride,
    const float* __restrict__ X,
    const float* __restrict__ Z,
    float* __restrict__ Y,
    int O, int K)
{
    const int M = 3 * N_;
    __shared__ float Ws[16][68];
    __shared__ float Xs[16][68];
    const int b  = blockIdx.z;
    const int m0 = blockIdx.x * 64;
    const int o0 = blockIdx.y * 64;
    const int tid = threadIdx.x;
    const int to = tid >> 4, tm = tid & 15;
    float acc[4][4] = {{0.f}};

    for (int kk = 0; kk < K; kk += 16) {
        {
            const int kidx = tid & 15, oo = tid >> 4;
            #pragma unroll
            for (int p = 0; p < 4; ++p) {
                int o = oo + p * 16;
                Ws[kidx][o] = W[(size_t)(o0 + o) * wstride + kk + kidx];
            }
        }
        if (XMODE == 0) {
            const int m = tid & 63, kr = tid >> 6;
            #pragma unroll
            for (int p = 0; p < 4; ++p) {
                int k = p * 4 + kr;
                Xs[k][m] = X[((size_t)b * K + kk + k) * M + m0 + m];
            }
        } else {
            const int kidx = tid & 15, nr = tid >> 4;
            #pragma unroll
            for (int p = 0; p < 4; ++p) {
                int mm = nr + p * 16;
                int mg = m0 + mm;
                int n = mg & (N_ - 1);
                int t = mg / N_;
                Xs[kidx][mm] = X[((size_t)(b * N_ + n) * 3 + t) * K + kk + kidx];
            }
        }
        __syncthreads();
        #pragma unroll
        for (int k = 0; k < 16; ++k) {
            float4 w4 = *(const float4*)&Ws[k][to * 4];
            float4 x4 = *(const float4*)&Xs[k][tm * 4];
            acc[0][0] += w4.x * x4.x; acc[0][1] += w4.x * x4.y; acc[0][2] += w4.x * x4.z; acc[0][3] += w4.x * x4.w;
            acc[1][0] += w4.y * x4.x; acc[1][1] += w4.y * x4.y; acc[1][2] += w4.y * x4.z; acc[1][3] += w4.y * x4.w;
            acc[2][0] += w4.z * x4.x; acc[2][1] += w4.z * x4.y; acc[2][2] += w4.z * x4.z; acc[2][3] += w4.z * x4.w;
            acc[3][0] += w4.w * x4.x; acc[3][1] += w4.w * x4.y; acc[3][2] += w4.w * x4.z; acc[3][3] += w4.w * x4.w;
        }
        __syncthreads();
    }
    #pragma unroll
    for (int i = 0; i < 4; ++i) {
        int o = o0 + to * 4 + i;
        size_t base = ((size_t)b * O + o) * M + m0 + tm * 4;
        float4 r;
        r.x = acc[i][0]; r.y = acc[i][1]; r.z = acc[i][2]; r.w = acc[i][3];
        if (Z) {
            float4 z4 = *(const float4*)&Z[base];
            r.x += z4.x; r.y += z4.y; r.z += z4.z; r.w += z4.w;
        }
        *(float4*)&Y[base] = r;
    }
}

// ---------------------------------------------------------------------------
// Flash attention over 48 joint (d,t) dims per head.
// Q/K/V head block = contiguous (48, N) rows at ((b*C + h*16)*3)*N.
// grid (N/64, B*HEADS), block 256 (4 waves). Wave wv owns output rows
// d in [wv*12, wv*12+12), lane = query column i.
// ---------------------------------------------------------------------------
__global__ __launch_bounds__(256) void attn_kernel(
    const float* __restrict__ lq, const float* __restrict__ lk,
    const float* __restrict__ lv, float* __restrict__ out)
{
    __shared__ float Ks[48][64];
    __shared__ float Vs[48][64];
    __shared__ float Pt[64][64];   // Pt[j][i]
    __shared__ float redm[4][64];
    __shared__ float redl[4][64];

    const int bh = blockIdx.y;
    const int b = bh >> 3, h = bh & 7;
    const int n0 = blockIdx.x * 64;
    const size_t hb = ((size_t)(b * C_ + h * 16)) * 3 * N_;
    const float* Q  = lq + hb;
    const float* Kp = lk + hb;
    const float* Vp = lv + hb;
    float* Op = out + hb;

    const int tid = threadIdx.x;
    const int lane = tid & 63, wv = tid >> 6;

    float qreg[48];
    #pragma unroll
    for (int d = 0; d < 48; ++d)
        qreg[d] = Q[(size_t)d * N_ + n0 + lane] * 0.14433756729740643f; // 1/sqrt(48)

    float acc[12];
    #pragma unroll
    for (int r = 0; r < 12; ++r) acc[r] = 0.f;
    float m_i = -1e30f, l_i = 0.f;

    for (int mt = 0; mt < N_ / 64; ++mt) {
        const int m0 = mt * 64;
        __syncthreads();
        for (int idx = tid; idx < 3072; idx += 256) {
            int d = idx >> 6, j = idx & 63;
            Ks[d][j] = Kp[(size_t)d * N_ + m0 + j];
            Vs[d][j] = Vp[(size_t)d * N_ + m0 + j];
        }
        __syncthreads();

        float s[16];
        #pragma unroll
        for (int jj = 0; jj < 16; ++jj) s[jj] = 0.f;
        #pragma unroll
        for (int d = 0; d < 48; ++d) {
            float qd = qreg[d];
            const float4* krow = (const float4*)&Ks[d][wv * 16];
            #pragma unroll
            for (int j4 = 0; j4 < 4; ++j4) {
                float4 kv = krow[j4];
                s[j4 * 4 + 0] += qd * kv.x; s[j4 * 4 + 1] += qd * kv.y;
                s[j4 * 4 + 2] += qd * kv.z; s[j4 * 4 + 3] += qd * kv.w;
            }
        }
        float pmax = -1e30f;
        #pragma unroll
        for (int jj = 0; jj < 16; ++jj) pmax = fmaxf(pmax, s[jj]);
        redm[wv][lane] = pmax;
        __syncthreads();
        float tmax = fmaxf(fmaxf(redm[0][lane], redm[1][lane]),
                           fmaxf(redm[2][lane], redm[3][lane]));
        float mnew = fmaxf(m_i, tmax);
        float sc_old = __expf(m_i - mnew);
        float psum = 0.f;
        #pragma unroll
        for (int jj = 0; jj < 16; ++jj) {
            float e = __expf(s[jj] - mnew);
            psum += e;
            Pt[wv * 16 + jj][lane] = e;
        }
        redl[wv][lane] = psum;
        __syncthreads();
        float tsum = redl[0][lane] + redl[1][lane] + redl[2][lane] + redl[3][lane];
        l_i = l_i * sc_old + tsum;
        m_i = mnew;
        #pragma unroll
        for (int r = 0; r < 12; ++r) acc[r] *= sc_old;
        #pragma unroll
        for (int j4 = 0; j4 < 16; ++j4) {
            float p0 = Pt[j4 * 4 + 0][lane];
            float p1 = Pt[j4 * 4 + 1][lane];
            float p2 = Pt[j4 * 4 + 2][lane];
            float p3 = Pt[j4 * 4 + 3][lane];
            #pragma unroll
            for (int r = 0; r < 12; ++r) {
                float4 v4 = *(const float4*)&Vs[wv * 12 + r][j4 * 4];
                acc[r] += p0 * v4.x + p1 * v4.y + p2 * v4.z + p3 * v4.w;
            }
        }
    }
    float inv_l = 1.f / l_i;
    #pragma unroll
    for (int r = 0; r < 12; ++r) {
        int d = wv * 12 + r;
        Op[(size_t)d * N_ + n0 + lane] = acc[r] * inv_l;
    }
}

// ---------------------------------------------------------------------------
// transpose (B,C,3,N) -> (B,N,3,C); grid (N/32, C/32, B*3), block 256
// ---------------------------------------------------------------------------
__global__ __launch_bounds__(256) void transpose_kernel(const float* __restrict__ x,
                                                        float* __restrict__ y)
{
    __shared__ float tile[32][33];
    const int z = blockIdx.z;
    const int b = z / 3, t = z % 3;
    const int n0 = blockIdx.x * 32, c0 = blockIdx.y * 32;
    const int tx = threadIdx.x & 31, ty = threadIdx.x >> 5;
    #pragma unroll
    for (int p = 0; p < 4; ++p) {
        int c = c0 + ty + p * 8;
        tile[ty + p * 8][tx] = x[((size_t)(b * C_ + c) * 3 + t) * N_ + n0 + tx];
    }
    __syncthreads();
    #pragma unroll
    for (int p = 0; p < 4; ++p) {
        int n = n0 + ty + p * 8;
        y[((size_t)(b * N_ + n) * 3 + t) * C_ + c0 + tx] = tile[tx][ty + p * 8];
    }
}

// ---------------------------------------------------------------------------
// graph attention core. tq/tv are (B,N,3,C) transposed LN'd tensors.
// per (b,n): s_k = <center, nbr_k>/sqrt(384); a = softmax_k;
// g[b,n,t,0:128]   = sum_k a_k nbr_k - center
// g[b,n,t,128:256] = center
// grid (N, B), block 256
// ---------------------------------------------------------------------------
__global__ __launch_bounds__(256) void graph_kernel(
    const float* __restrict__ tq, const float* __restrict__ tv,
    const int* __restrict__ idx, float* __restrict__ g)
{
    __shared__ float center[384];
    __shared__ float sd[16];
    __shared__ int nbr_i[16];
    const int b = blockIdx.y, n = blockIdx.x;
    const int tid = threadIdx.x;
    const float* qrow = tq + (size_t)(b * N_ + n) * 384;
    for (int e = tid; e < 384; e += 256) center[e] = qrow[e];
    if (tid < 16) nbr_i[tid] = idx[(size_t)(b * N_ + n) * 16 + tid];
    __syncthreads();

    const int lane = tid & 63, wv = tid >> 6;
    for (int kk = 0; kk < 4; ++kk) {
        int k = wv * 4 + kk;
        const float* vrow = tv + ((size_t)b * N_ + nbr_i[k]) * 384;
        float p = 0.f;
        #pragma unroll
        for (int jj = 0; jj < 6; ++jj) {
            int e = lane + jj * 64;
            p += center[e] * vrow[e];
        }
        #pragma unroll
        for (int off = 32; off; off >>= 1) p += __shfl_down(p, off, 64);
        if (lane == 0) sd[k] = p * 0.05103103630798288f; // 1/sqrt(384)
    }
    __syncthreads();

    float mx = -1e30f;
    #pragma unroll
    for (int k = 0; k < 16; ++k) mx = fmaxf(mx, sd[k]);
    float a[16]; float ssum = 0.f;
    #pragma unroll
    for (int k = 0; k < 16; ++k) { a[k] = __expf(sd[k] - mx); ssum += a[k]; }
    float inv = 1.f / ssum;

    for (int e = tid; e < 384; e += 256) {
        float accv = 0.f;
        #pragma unroll
        for (int k = 0; k < 16; ++k)
            accv += a[k] * tv[((size_t)b * N_ + nbr_i[k]) * 384 + e];
        accv *= inv;
        float ce = center[e];
        int t = e >> 7, c = e & 127;
        size_t gb = ((size_t)(b * N_ + n) * 3 + t) * 256;
        g[gb + c]       = accv - ce;
        g[gb + 128 + c] = ce;
    }
}

// ---------------------------------------------------------------------------
// vn_leaky: per (b,hid,n) 3-vector x, d: dot=<x,d>, dsq=<d,d>
// y = NS*x + (1-NS)*(dot>=0 ? x : x - dot/(dsq+eps)*d)
// ---------------------------------------------------------------------------
__global__ __launch_bounds__(256) void leaky_kernel(const float* __restrict__ x,
                                                    const float* __restrict__ d,
                                                    float* __restrict__ y)
{
    size_t p = (size_t)blockIdx.x * 256 + threadIdx.x;
    size_t bh = p / N_, n = p % N_;
    size_t base = bh * 3 * N_ + n;
    float x0 = x[base], x1 = x[base + N_], x2 = x[base + 2 * N_];
    float d0 = d[base], d1 = d[base + N_], d2 = d[base + 2 * N_];
    float dot = x0 * d0 + x1 * d1 + x2 * d2;
    float dsq = d0 * d0 + d1 * d1 + d2 * d2;
    float f = dot / (dsq + EPS_);
    bool pos = dot >= 0.f;
    float y0 = pos ? x0 : x0 - f * d0;
    float y1 = pos ? x1 : x1 - f * d1;
    float y2 = pos ? x2 : x2 - f * d2;
    y[base]          = NS_ * x0 + (1.f - NS_) * y0;
    y[base + N_]     = NS_ * x1 + (1.f - NS_) * y1;
    y[base + 2 * N_] = NS_ * x2 + (1.f - NS_) * y2;
}

// ---------------------------------------------------------------------------
extern "C" void kernel_launch(void* const* d_in, const int* in_sizes, int n_in,
                              void* d_out, int out_size, void* d_ws, size_t ws_size,
                              hipStream_t stream)
{
    const float* q_in = (const float*)d_in[0];
    const float* v_in = (const float*)d_in[1];
    const int*   idx_s = (const int*)d_in[4];
    const int*   idx_c = (const int*)d_in[5];
    const float* g1 = (const float*)d_in[6];
    const float* b1 = (const float*)d_in[7];
    const float* g2 = (const float*)d_in[8];
    const float* b2 = (const float*)d_in[9];
    const float* gq = (const float*)d_in[10];
    const float* bq = (const float*)d_in[11];
    const float* gv = (const float*)d_in[12];
    const float* bv = (const float*)d_in[13];
    const float* Wq_s = (const float*)d_in[14];
    const float* Wk_s = (const float*)d_in[15];
    const float* Wv_s = (const float*)d_in[16];
    const float* Wo_s = (const float*)d_in[17];
    const float* We_s = (const float*)d_in[18];
    const float* Wm_s = (const float*)d_in[19];
    const float* Wq_c = (const float*)d_in[20];
    const float* Wk_c = (const float*)d_in[21];
    const float* Wv_c = (const float*)d_in[22];
    const float* Wo_c = (const float*)d_in[23];
    const float* We_c = (const float*)d_in[24];
    const float* Wm_c = (const float*)d_in[25];
    const float* W1   = (const float*)d_in[26];
    const float* Dact = (const float*)d_in[27];
    const float* W2   = (const float*)d_in[28];
    float* out = (float*)d_out;
    float* ws  = (float*)d_ws;

    const size_t S1 = (size_t)B_ * C_ * 3 * N_; // 1572864 floats
    float* nx   = ws;
    float* nv   = ws + S1;
    float* t1   = ws + 2 * S1;
    float* t2   = ws + 3 * S1;
    float* lq   = ws + 4 * S1;
    float* lk   = ws + 5 * S1;
    float* lv   = ws + 6 * S1;
    float* ao   = ws + 7 * S1;
    float* f1   = ws + 8 * S1;
    float* f2   = ws + 9 * S1;
    float* gbuf = ws + 10 * S1;      // 2*S1
    float* qa   = ws + 12 * S1;
    float* qb   = ws + 13 * S1;
    float* h1   = ws + 2 * S1;       // phase C alias (t1,t2,lq,lk dead)
    float* hd   = ws + 6 * S1;       // phase C alias (lv,ao,f1,f2 dead)

    const int M = 3 * N_;
    dim3 gln(N_ / 32, B_);
    dim3 gtr(N_ / 32, C_ / 32, B_ * 3);
    dim3 gat(N_ / 64, B_ * HEADS_);
    dim3 ggr(N_, B_);

    auto gemm0 = [&](const float* W, int wstr, const float* X, const float* Z,
                     float* Y, int O, int K) {
        dim3 g(M / 64, O / 64, B_);
        gemm_kernel<0><<<g, 256, 0, stream>>>(W, wstr, X, Z, Y, O, K);
    };
    auto gemm1 = [&](const float* W, int wstr, const float* X, const float* Z,
                     float* Y, int O, int K) {
        dim3 g(M / 64, O / 64, B_);
        gemm_kernel<1><<<g, 256, 0, stream>>>(W, wstr, X, Z, Y, O, K);
    };

    // ---- Phase A: self attention block ----
    ln_kernel<<<gln, 256, 0, stream>>>(q_in, g1, b1, nx);
    gemm0(Wq_s, 128, nx, nullptr, lq, 128, 128);
    gemm0(Wk_s, 128, nx, nullptr, lk, 128, 128);
    gemm0(Wv_s, 128, nx, nullptr, lv, 128, 128);
    attn_kernel<<<gat, 256, 0, stream>>>(lq, lk, lv, ao);
    gemm0(Wo_s, 128, ao, nullptr, f1, 128, 128);
    transpose_kernel<<<gtr, 256, 0, stream>>>(nx, t1);
    graph_kernel<<<ggr, 256, 0, stream>>>(t1, t1, idx_s, gbuf);
    gemm1(We_s, 256, gbuf, nullptr, f2, 128, 256);
    gemm0(Wm_s,       256, f1, q_in, qa, 128, 128);
    gemm0(Wm_s + 128, 256, f2, qa,   qa, 128, 128);

    // ---- Phase B: cross attention block ----
    ln_kernel<<<gln, 256, 0, stream>>>(qa,   gq, bq, nx);
    ln_kernel<<<gln, 256, 0, stream>>>(v_in, gv, bv, nv);
    gemm0(Wq_c, 128, nx, nullptr, lq, 128, 128);
    gemm0(Wk_c, 128, nv, nullptr, lk, 128, 128);
    gemm0(Wv_c, 128, nv, nullptr, lv, 128, 128);
    attn_kernel<<<gat, 256, 0, stream>>>(lq, lk, lv, ao);
    gemm0(Wo_c, 128, ao, nullptr, f1, 128, 128);
    transpose_kernel<<<gtr, 256, 0, stream>>>(nx, t1);
    transpose_kernel<<<gtr, 256, 0, stream>>>(nv, t2);
    graph_kernel<<<ggr, 256, 0, stream>>>(t1, t2, idx_c, gbuf);
    gemm1(We_c, 256, gbuf, nullptr, f2, 128, 256);
    gemm0(Wm_c,       256, f1, qa, qb, 128, 128);
    gemm0(Wm_c + 128, 256, f2, qb, qb, 128, 128);

    // ---- Phase C: vector MLP ----
    ln_kernel<<<gln, 256, 0, stream>>>(qb, g2, b2, nx);
    gemm0(W1,   128, nx, nullptr, h1, 512, 128);
    gemm0(Dact, 512, h1, nullptr, hd, 512, 512);
    leaky_kernel<<<dim3((B_ * HID_ * N_) / 256), 256, 0, stream>>>(h1, hd, h1);
    gemm0(W2,   512, h1, qb, out, 128, 512);
}

// Round 2
// 584.481 us; speedup vs baseline: 3.1413x; 3.1413x over previous
//
#include <hip/hip_runtime.h>
#include <math.h>

#define B_    2
#define C_    128
#define N_    2048
#define HID_  512
#define HEADS_ 8
#define EPS_  1e-6f
#define NS_   0.2f

typedef __attribute__((ext_vector_type(8))) short short8v;  // 8 bf16
typedef __attribute__((ext_vector_type(4))) float f32x4;

__device__ inline unsigned short f2bf(float f) {
    unsigned u = __float_as_uint(f);
    u += 0x7FFF + ((u >> 16) & 1);          // round-to-nearest-even
    return (unsigned short)(u >> 16);
}

// ---------------------------------------------------------------------------
// vec_layernorm (unchanged)
// ---------------------------------------------------------------------------
__global__ __launch_bounds__(256) void ln_kernel(const float* __restrict__ x,
        const float* __restrict__ gma, const float* __restrict__ bta,
        float* __restrict__ y)
{
    __shared__ float norms[128][32];
    __shared__ float red1[8][32];
    __shared__ float red2[8][32];
    const int b  = blockIdx.y;
    const int n0 = blockIdx.x * 32;
    const int nn = threadIdx.x & 31;
    const int cg = threadIdx.x >> 5;

    float s1 = 0.f, s2 = 0.f;
    for (int it = 0; it < 16; ++it) {
        int c = it * 8 + cg;
        size_t base = ((size_t)(b * C_ + c) * 3) * N_ + n0 + nn;
        float x0 = x[base], x1 = x[base + N_], x2 = x[base + 2 * N_];
        float nr = sqrtf(x0 * x0 + x1 * x1 + x2 * x2 + EPS_);
        norms[c][nn] = nr;
        s1 += nr; s2 += nr * nr;
    }
    red1[cg][nn] = s1; red2[cg][nn] = s2;
    __syncthreads();
    float S1 = 0.f, S2 = 0.f;
    #pragma unroll
    for (int g = 0; g < 8; ++g) { S1 += red1[g][nn]; S2 += red2[g][nn]; }
    float mu   = S1 * (1.f / 128.f);
    float var  = S2 * (1.f / 128.f) - mu * mu;
    float rstd = rsqrtf(var + EPS_);

    for (int it = 0; it < 16; ++it) {
        int c = it * 8 + cg;
        float nr = norms[c][nn];
        float ln = (nr - mu) * rstd * gma[c] + bta[c];
        float sc = ln / (nr + EPS_);
        size_t base = ((size_t)(b * C_ + c) * 3) * N_ + n0 + nn;
        y[base]          = x[base] * sc;
        y[base + N_]     = x[base + N_] * sc;
        y[base + 2 * N_] = x[base + 2 * N_] * sc;
    }
}

// ---------------------------------------------------------------------------
// fp32 GEMM (unchanged)
// ---------------------------------------------------------------------------
template <int XMODE>
__global__ __launch_bounds__(256) void gemm_kernel(
    const float* __restrict__ W, int wstride,
    const float* __restrict__ X,
    const float* __restrict__ Z,
    float* __restrict__ Y,
    int O, int K)
{
    const int M = 3 * N_;
    __shared__ float Ws[16][68];
    __shared__ float Xs[16][68];
    const int b  = blockIdx.z;
    const int m0 = blockIdx.x * 64;
    const int o0 = blockIdx.y * 64;
    const int tid = threadIdx.x;
    const int to = tid >> 4, tm = tid & 15;
    float acc[4][4] = {{0.f}};

    for (int kk = 0; kk < K; kk += 16) {
        {
            const int kidx = tid & 15, oo = tid >> 4;
            #pragma unroll
            for (int p = 0; p < 4; ++p) {
                int o = oo + p * 16;
                Ws[kidx][o] = W[(size_t)(o0 + o) * wstride + kk + kidx];
            }
        }
        if (XMODE == 0) {
            const int m = tid & 63, kr = tid >> 6;
            #pragma unroll
            for (int p = 0; p < 4; ++p) {
                int k = p * 4 + kr;
                Xs[k][m] = X[((size_t)b * K + kk + k) * M + m0 + m];
            }
        } else {
            const int kidx = tid & 15, nr = tid >> 4;
            #pragma unroll
            for (int p = 0; p < 4; ++p) {
                int mm = nr + p * 16;
                int mg = m0 + mm;
                int n = mg & (N_ - 1);
                int t = mg / N_;
                Xs[kidx][mm] = X[((size_t)(b * N_ + n) * 3 + t) * K + kk + kidx];
            }
        }
        __syncthreads();
        #pragma unroll
        for (int k = 0; k < 16; ++k) {
            float4 w4 = *(const float4*)&Ws[k][to * 4];
            float4 x4 = *(const float4*)&Xs[k][tm * 4];
            acc[0][0] += w4.x * x4.x; acc[0][1] += w4.x * x4.y; acc[0][2] += w4.x * x4.z; acc[0][3] += w4.x * x4.w;
            acc[1][0] += w4.y * x4.x; acc[1][1] += w4.y * x4.y; acc[1][2] += w4.y * x4.z; acc[1][3] += w4.y * x4.w;
            acc[2][0] += w4.z * x4.x; acc[2][1] += w4.z * x4.y; acc[2][2] += w4.z * x4.z; acc[2][3] += w4.z * x4.w;
            acc[3][0] += w4.w * x4.x; acc[3][1] += w4.w * x4.y; acc[3][2] += w4.w * x4.z; acc[3][3] += w4.w * x4.w;
        }
        __syncthreads();
    }
    #pragma unroll
    for (int i = 0; i < 4; ++i) {
        int o = o0 + to * 4 + i;
        size_t base = ((size_t)b * O + o) * M + m0 + tm * 4;
        float4 r;
        r.x = acc[i][0]; r.y = acc[i][1]; r.z = acc[i][2]; r.w = acc[i][3];
        if (Z) {
            float4 z4 = *(const float4*)&Z[base];
            r.x += z4.x; r.y += z4.y; r.z += z4.z; r.w += z4.w;
        }
        *(float4*)&Y[base] = r;
    }
}

// ---------------------------------------------------------------------------
// bf16 MFMA flash attention. Per (b,h): rows = 48 joint (c_local,t) dims,
// layout (48, N) at hb. Swapped orientation: S^T[key][query] = K^T·Q so each
// lane owns ONE query column and 16 key-scores per 64-key tile.
// Block: 256 thr = 4 waves, 64 queries (16/wave). Grid (N/64, B*HEADS).
//
// MFMA 16x16x32 layouts (guide §3, m89/m162):
//   A[row][k]: row = lane&15, k = (lane>>4)*8 + j
//   B[k][col]: col = lane&15, k = (lane>>4)*8 + j
//   D[row][col]: col = lane&15, row = (lane>>4)*4 + r
// ---------------------------------------------------------------------------
#define LDT 72   // LDS row stride (bf16 elems) = 144 B -> bank 4*row%32, ~2-way

__global__ __launch_bounds__(256) void attn_mfma_kernel(
    const float* __restrict__ lq, const float* __restrict__ lk,
    const float* __restrict__ lv, float* __restrict__ out)
{
    __shared__ __align__(16) unsigned short Qt[64][LDT];   // [query][d], cols 48..63 = 0
    __shared__ __align__(16) unsigned short Kt[64][LDT];   // [key][d],   cols 48..63 = 0
    __shared__ __align__(16) unsigned short Vs[48][LDT];   // [d][key]
    __shared__ __align__(16) unsigned short Pl[4][16][LDT];// per-wave [query][key]

    const int bh = blockIdx.y;
    const int b = bh >> 3, h = bh & 7;
    const int n0 = blockIdx.x * 64;
    const size_t hb = ((size_t)(b * C_ + h * 16)) * 3 * N_;
    const float* Q  = lq + hb;
    const float* Kp = lk + hb;
    const float* Vp = lv + hb;
    float* Op = out + hb;

    const int tid = threadIdx.x;
    const int lane = tid & 63, wv = tid >> 6;
    const int col = lane & 15, grp = lane >> 4;

    // ---- stage Q transposed (scaled by 1/sqrt(48)), zero-pad d=48..63 ----
    {
        const int m = tid & 63;
        const int dq = (tid >> 6) * 4;
        #pragma unroll
        for (int p = 0; p < 3; ++p) {
            int d0 = p * 16 + dq;
            const float* src = Q + (size_t)d0 * N_ + n0 + m;
            ushort4 pk;
            pk.x = f2bf(src[0]      * 0.14433756729740643f);
            pk.y = f2bf(src[N_]     * 0.14433756729740643f);
            pk.z = f2bf(src[2 * N_] * 0.14433756729740643f);
            pk.w = f2bf(src[3 * N_] * 0.14433756729740643f);
            *(ushort4*)&Qt[m][d0] = pk;
        }
        ushort4 z4; z4.x = z4.y = z4.z = z4.w = 0;
        *(ushort4*)&Qt[m][48 + dq] = z4;
        *(ushort4*)&Kt[m][48 + dq] = z4;
    }
    __syncthreads();
    short8v qf0 = *(const short8v*)&Qt[wv * 16 + col][grp * 8];
    short8v qf1 = *(const short8v*)&Qt[wv * 16 + col][32 + grp * 8];

    f32x4 acc[3];
    #pragma unroll
    for (int db = 0; db < 3; ++db) { f32x4 z = {0.f, 0.f, 0.f, 0.f}; acc[db] = z; }
    float m_i = -1e30f, l_i = 0.f;

    for (int mt = 0; mt < N_ / 64; ++mt) {
        const int m0 = mt * 64;
        __syncthreads();
        // stage K transposed: Kt[key][d] (bf16)
        {
            const int m = tid & 63;
            const int dq = (tid >> 6) * 4;
            #pragma unroll
            for (int p = 0; p < 3; ++p) {
                int d0 = p * 16 + dq;
                const float* src = Kp + (size_t)d0 * N_ + m0 + m;
                ushort4 pk;
                pk.x = f2bf(src[0]);
                pk.y = f2bf(src[N_]);
                pk.z = f2bf(src[2 * N_]);
                pk.w = f2bf(src[3 * N_]);
                *(ushort4*)&Kt[m][d0] = pk;
            }
        }
        // stage V direct: Vs[d][key] (bf16)
        {
            const int m2 = (tid & 31) * 2;
            const int dr = tid >> 5;
            #pragma unroll
            for (int p = 0; p < 6; ++p) {
                int d = p * 8 + dr;
                float2 v2 = *(const float2*)&Vp[(size_t)d * N_ + m0 + m2];
                ushort2 pk;
                pk.x = f2bf(v2.x);
                pk.y = f2bf(v2.y);
                *(ushort2*)&Vs[d][m2] = pk;
            }
        }
        __syncthreads();

        // ---- QK^T (swapped): sf[kb] rows = keys kb*16+grp*4+r, col = query
        f32x4 sf[4];
        #pragma unroll
        for (int kb = 0; kb < 4; ++kb) {
            short8v ka0 = *(const short8v*)&Kt[kb * 16 + col][grp * 8];
            short8v ka1 = *(const short8v*)&Kt[kb * 16 + col][32 + grp * 8];
            f32x4 z = {0.f, 0.f, 0.f, 0.f};
            z = __builtin_amdgcn_mfma_f32_16x16x32_bf16(ka0, qf0, z, 0, 0, 0);
            z = __builtin_amdgcn_mfma_f32_16x16x32_bf16(ka1, qf1, z, 0, 0, 0);
            sf[kb] = z;
        }

        // ---- online softmax: row = query, distributed over xor-group {16,32}
        float pmax = -1e30f;
        #pragma unroll
        for (int kb = 0; kb < 4; ++kb)
            #pragma unroll
            for (int r = 0; r < 4; ++r) pmax = fmaxf(pmax, sf[kb][r]);
        pmax = fmaxf(pmax, __shfl_xor(pmax, 16, 64));
        pmax = fmaxf(pmax, __shfl_xor(pmax, 32, 64));
        float mnew = fmaxf(m_i, pmax);
        float sc_old = __expf(m_i - mnew);
        float psum = 0.f;
        #pragma unroll
        for (int kb = 0; kb < 4; ++kb) {
            float e0 = __expf(sf[kb][0] - mnew);
            float e1 = __expf(sf[kb][1] - mnew);
            float e2 = __expf(sf[kb][2] - mnew);
            float e3 = __expf(sf[kb][3] - mnew);
            psum += e0 + e1 + e2 + e3;
            ushort4 pk;
            pk.x = f2bf(e0); pk.y = f2bf(e1); pk.z = f2bf(e2); pk.w = f2bf(e3);
            *(ushort4*)&Pl[wv][col][kb * 16 + grp * 4] = pk;
        }
        psum += __shfl_xor(psum, 16, 64);
        psum += __shfl_xor(psum, 32, 64);
        l_i = l_i * sc_old + psum;
        m_i = mnew;
        #pragma unroll
        for (int db = 0; db < 3; ++db) {
            acc[db][0] *= sc_old; acc[db][1] *= sc_old;
            acc[db][2] *= sc_old; acc[db][3] *= sc_old;
        }

        // ---- PV: acc[db] += V[db-block] · P
        #pragma unroll
        for (int hh = 0; hh < 2; ++hh) {
            short8v pf = *(const short8v*)&Pl[wv][col][hh * 32 + grp * 8];
            #pragma unroll
            for (int db = 0; db < 3; ++db) {
                short8v vf = *(const short8v*)&Vs[db * 16 + col][hh * 32 + grp * 8];
                acc[db] = __builtin_amdgcn_mfma_f32_16x16x32_bf16(vf, pf, acc[db], 0, 0, 0);
            }
        }
    }

    const float inv = 1.f / l_i;
    #pragma unroll
    for (int db = 0; db < 3; ++db)
        #pragma unroll
        for (int r = 0; r < 4; ++r) {
            int d = db * 16 + grp * 4 + r;
            Op[(size_t)d * N_ + n0 + wv * 16 + col] = acc[db][r] * inv;
        }
}

// ---------------------------------------------------------------------------
// transpose (unchanged)
// ---------------------------------------------------------------------------
__global__ __launch_bounds__(256) void transpose_kernel(const float* __restrict__ x,
                                                        float* __restrict__ y)
{
    __shared__ float tile[32][33];
    const int z = blockIdx.z;
    const int b = z / 3, t = z % 3;
    const int n0 = blockIdx.x * 32, c0 = blockIdx.y * 32;
    const int tx = threadIdx.x & 31, ty = threadIdx.x >> 5;
    #pragma unroll
    for (int p = 0; p < 4; ++p) {
        int c = c0 + ty + p * 8;
        tile[ty + p * 8][tx] = x[((size_t)(b * C_ + c) * 3 + t) * N_ + n0 + tx];
    }
    __syncthreads();
    #pragma unroll
    for (int p = 0; p < 4; ++p) {
        int n = n0 + ty + p * 8;
        y[((size_t)(b * N_ + n) * 3 + t) * C_ + c0 + tx] = tile[tx][ty + p * 8];
    }
}

// ---------------------------------------------------------------------------
// graph attention (unchanged)
// ---------------------------------------------------------------------------
__global__ __launch_bounds__(256) void graph_kernel(
    const float* __restrict__ tq, const float* __restrict__ tv,
    const int* __restrict__ idx, float* __restrict__ g)
{
    __shared__ float center[384];
    __shared__ float sd[16];
    __shared__ int nbr_i[16];
    const int b = blockIdx.y, n = blockIdx.x;
    const int tid = threadIdx.x;
    const float* qrow = tq + (size_t)(b * N_ + n) * 384;
    for (int e = tid; e < 384; e += 256) center[e] = qrow[e];
    if (tid < 16) nbr_i[tid] = idx[(size_t)(b * N_ + n) * 16 + tid];
    __syncthreads();

    const int lane = tid & 63, wv = tid >> 6;
    for (int kk = 0; kk < 4; ++kk) {
        int k = wv * 4 + kk;
        const float* vrow = tv + ((size_t)b * N_ + nbr_i[k]) * 384;
        float p = 0.f;
        #pragma unroll
        for (int jj = 0; jj < 6; ++jj) {
            int e = lane + jj * 64;
            p += center[e] * vrow[e];
        }
        #pragma unroll
        for (int off = 32; off; off >>= 1) p += __shfl_down(p, off, 64);
        if (lane == 0) sd[k] = p * 0.05103103630798288f;
    }
    __syncthreads();

    float mx = -1e30f;
    #pragma unroll
    for (int k = 0; k < 16; ++k) mx = fmaxf(mx, sd[k]);
    float a[16]; float ssum = 0.f;
    #pragma unroll
    for (int k = 0; k < 16; ++k) { a[k] = __expf(sd[k] - mx); ssum += a[k]; }
    float inv = 1.f / ssum;

    for (int e = tid; e < 384; e += 256) {
        float accv = 0.f;
        #pragma unroll
        for (int k = 0; k < 16; ++k)
            accv += a[k] * tv[((size_t)b * N_ + nbr_i[k]) * 384 + e];
        accv *= inv;
        float ce = center[e];
        int t = e >> 7, c = e & 127;
        size_t gb = ((size_t)(b * N_ + n) * 3 + t) * 256;
        g[gb + c]       = accv - ce;
        g[gb + 128 + c] = ce;
    }
}

// ---------------------------------------------------------------------------
// vn_leaky (unchanged)
// ---------------------------------------------------------------------------
__global__ __launch_bounds__(256) void leaky_kernel(const float* __restrict__ x,
                                                    const float* __restrict__ d,
                                                    float* __restrict__ y)
{
    size_t p = (size_t)blockIdx.x * 256 + threadIdx.x;
    size_t bh = p / N_, n = p % N_;
    size_t base = bh * 3 * N_ + n;
    float x0 = x[base], x1 = x[base + N_], x2 = x[base + 2 * N_];
    float d0 = d[base], d1 = d[base + N_], d2 = d[base + 2 * N_];
    float dot = x0 * d0 + x1 * d1 + x2 * d2;
    float dsq = d0 * d0 + d1 * d1 + d2 * d2;
    float f = dot / (dsq + EPS_);
    bool pos = dot >= 0.f;
    float y0 = pos ? x0 : x0 - f * d0;
    float y1 = pos ? x1 : x1 - f * d1;
    float y2 = pos ? x2 : x2 - f * d2;
    y[base]          = NS_ * x0 + (1.f - NS_) * y0;
    y[base + N_]     = NS_ * x1 + (1.f - NS_) * y1;
    y[base + 2 * N_] = NS_ * x2 + (1.f - NS_) * y2;
}

// ---------------------------------------------------------------------------
extern "C" void kernel_launch(void* const* d_in, const int* in_sizes, int n_in,
                              void* d_out, int out_size, void* d_ws, size_t ws_size,
                              hipStream_t stream)
{
    const float* q_in = (const float*)d_in[0];
    const float* v_in = (const float*)d_in[1];
    const int*   idx_s = (const int*)d_in[4];
    const int*   idx_c = (const int*)d_in[5];
    const float* g1 = (const float*)d_in[6];
    const float* b1 = (const float*)d_in[7];
    const float* g2 = (const float*)d_in[8];
    const float* b2 = (const float*)d_in[9];
    const float* gq = (const float*)d_in[10];
    const float* bq = (const float*)d_in[11];
    const float* gv = (const float*)d_in[12];
    const float* bv = (const float*)d_in[13];
    const float* Wq_s = (const float*)d_in[14];
    const float* Wk_s = (const float*)d_in[15];
    const float* Wv_s = (const float*)d_in[16];
    const float* Wo_s = (const float*)d_in[17];
    const float* We_s = (const float*)d_in[18];
    const float* Wm_s = (const float*)d_in[19];
    const float* Wq_c = (const float*)d_in[20];
    const float* Wk_c = (const float*)d_in[21];
    const float* Wv_c = (const float*)d_in[22];
    const float* Wo_c = (const float*)d_in[23];
    const float* We_c = (const float*)d_in[24];
    const float* Wm_c = (const float*)d_in[25];
    const float* W1   = (const float*)d_in[26];
    const float* Dact = (const float*)d_in[27];
    const float* W2   = (const float*)d_in[28];
    float* out = (float*)d_out;
    float* ws  = (float*)d_ws;

    const size_t S1 = (size_t)B_ * C_ * 3 * N_; // 1572864 floats
    float* nx   = ws;
    float* nv   = ws + S1;
    float* t1   = ws + 2 * S1;
    float* t2   = ws + 3 * S1;
    float* lq   = ws + 4 * S1;
    float* lk   = ws + 5 * S1;
    float* lv   = ws + 6 * S1;
    float* ao   = ws + 7 * S1;
    float* f1   = ws + 8 * S1;
    float* f2   = ws + 9 * S1;
    float* gbuf = ws + 10 * S1;      // 2*S1
    float* qa   = ws + 12 * S1;
    float* qb   = ws + 13 * S1;
    float* h1   = ws + 2 * S1;       // phase C alias (t1,t2,lq,lk dead)
    float* hd   = ws + 6 * S1;       // phase C alias (lv,ao,f1,f2 dead)

    const int M = 3 * N_;
    dim3 gln(N_ / 32, B_);
    dim3 gtr(N_ / 32, C_ / 32, B_ * 3);
    dim3 gat(N_ / 64, B_ * HEADS_);
    dim3 ggr(N_, B_);

    auto gemm0 = [&](const float* W, int wstr, const float* X, const float* Z,
                     float* Y, int O, int K) {
        dim3 g(M / 64, O / 64, B_);
        gemm_kernel<0><<<g, 256, 0, stream>>>(W, wstr, X, Z, Y, O, K);
    };
    auto gemm1 = [&](const float* W, int wstr, const float* X, const float* Z,
                     float* Y, int O, int K) {
        dim3 g(M / 64, O / 64, B_);
        gemm_kernel<1><<<g, 256, 0, stream>>>(W, wstr, X, Z, Y, O, K);
    };

    // ---- Phase A: self attention block ----
    ln_kernel<<<gln, 256, 0, stream>>>(q_in, g1, b1, nx);
    gemm0(Wq_s, 128, nx, nullptr, lq, 128, 128);
    gemm0(Wk_s, 128, nx, nullptr, lk, 128, 128);
    gemm0(Wv_s, 128, nx, nullptr, lv, 128, 128);
    attn_mfma_kernel<<<gat, 256, 0, stream>>>(lq, lk, lv, ao);
    gemm0(Wo_s, 128, ao, nullptr, f1, 128, 128);
    transpose_kernel<<<gtr, 256, 0, stream>>>(nx, t1);
    graph_kernel<<<ggr, 256, 0, stream>>>(t1, t1, idx_s, gbuf);
    gemm1(We_s, 256, gbuf, nullptr, f2, 128, 256);
    gemm0(Wm_s,       256, f1, q_in, qa, 128, 128);
    gemm0(Wm_s + 128, 256, f2, qa,   qa, 128, 128);

    // ---- Phase B: cross attention block ----
    ln_kernel<<<gln, 256, 0, stream>>>(qa,   gq, bq, nx);
    ln_kernel<<<gln, 256, 0, stream>>>(v_in, gv, bv, nv);
    gemm0(Wq_c, 128, nx, nullptr, lq, 128, 128);
    gemm0(Wk_c, 128, nv, nullptr, lk, 128, 128);
    gemm0(Wv_c, 128, nv, nullptr, lv, 128, 128);
    attn_mfma_kernel<<<gat, 256, 0, stream>>>(lq, lk, lv, ao);
    gemm0(Wo_c, 128, ao, nullptr, f1, 128, 128);
    transpose_kernel<<<gtr, 256, 0, stream>>>(nx, t1);
    transpose_kernel<<<gtr, 256, 0, stream>>>(nv, t2);
    graph_kernel<<<ggr, 256, 0, stream>>>(t1, t2, idx_c, gbuf);
    gemm1(We_c, 256, gbuf, nullptr, f2, 128, 256);
    gemm0(Wm_c,       256, f1, qa, qb, 128, 128);
    gemm0(Wm_c + 128, 256, f2, qb, qb, 128, 128);

    // ---- Phase C: vector MLP ----
    ln_kernel<<<gln, 256, 0, stream>>>(qb, g2, b2, nx);
    gemm0(W1,   128, nx, nullptr, h1, 512, 128);
    gemm0(Dact, 512, h1, nullptr, hd, 512, 512);
    leaky_kernel<<<dim3((B_ * HID_ * N_) / 256), 256, 0, stream>>>(h1, hd, h1);
    gemm0(W2,   512, h1, qb, out, 128, 512);
}

// Round 4
// 360.379 us; speedup vs baseline: 5.0948x; 1.6218x over previous
//
#include <hip/hip_runtime.h>
#include <math.h>

#define B_    2
#define C_    128
#define N_    2048
#define HID_  512
#define HEADS_ 8
#define EPS_  1e-6f
#define NS_   0.2f

typedef __attribute__((ext_vector_type(8))) short short8v;  // 8 bf16
typedef __attribute__((ext_vector_type(4))) float f32x4;
typedef unsigned short ush;
typedef unsigned int u32;

__device__ inline ush f2bf(float f) {
    unsigned u = __float_as_uint(f);
    u += 0x7FFF + ((u >> 16) & 1);          // round-to-nearest-even
    return (ush)(u >> 16);
}

// pack float -> (hi bf16 << 16) | lo bf16, with hi+lo ~ x to ~2^-17 rel
__device__ inline u32 splitpack(float x) {
    ush hi = f2bf(x);
    float hf = __uint_as_float((u32)hi << 16);
    ush lo = f2bf(x - hf);
    return ((u32)hi << 16) | (u32)lo;
}

__device__ inline void unpack16(const u32* buf, short8v& h0, short8v& h1,
                                short8v& l0, short8v& l1) {
    ush h[16], l[16];
    #pragma unroll
    for (int j = 0; j < 16; ++j) { u32 u = buf[j]; h[j] = (ush)(u >> 16); l[j] = (ush)(u & 0xffff); }
    h0 = *(short8v*)&h[0]; h1 = *(short8v*)&h[8];
    l0 = *(short8v*)&l[0]; l1 = *(short8v*)&l[8];
}

// ---------------------------------------------------------------------------
// vec_layernorm: writes fp32 y AND split plane ysp
// ---------------------------------------------------------------------------
__global__ __launch_bounds__(256) void ln_kernel(const float* __restrict__ x,
        const float* __restrict__ gma, const float* __restrict__ bta,
        float* __restrict__ y, u32* __restrict__ ysp)
{
    __shared__ float norms[128][32];
    __shared__ float red1[8][32];
    __shared__ float red2[8][32];
    const int b  = blockIdx.y;
    const int n0 = blockIdx.x * 32;
    const int nn = threadIdx.x & 31;
    const int cg = threadIdx.x >> 5;

    float s1 = 0.f, s2 = 0.f;
    for (int it = 0; it < 16; ++it) {
        int c = it * 8 + cg;
        size_t base = ((size_t)(b * C_ + c) * 3) * N_ + n0 + nn;
        float x0 = x[base], x1 = x[base + N_], x2 = x[base + 2 * N_];
        float nr = sqrtf(x0 * x0 + x1 * x1 + x2 * x2 + EPS_);
        norms[c][nn] = nr;
        s1 += nr; s2 += nr * nr;
    }
    red1[cg][nn] = s1; red2[cg][nn] = s2;
    __syncthreads();
    float S1 = 0.f, S2 = 0.f;
    #pragma unroll
    for (int g = 0; g < 8; ++g) { S1 += red1[g][nn]; S2 += red2[g][nn]; }
    float mu   = S1 * (1.f / 128.f);
    float var  = S2 * (1.f / 128.f) - mu * mu;
    float rstd = rsqrtf(var + EPS_);

    for (int it = 0; it < 16; ++it) {
        int c = it * 8 + cg;
        float nr = norms[c][nn];
        float ln = (nr - mu) * rstd * gma[c] + bta[c];
        float sc = ln / (nr + EPS_);
        size_t base = ((size_t)(b * C_ + c) * 3) * N_ + n0 + nn;
        float y0 = x[base] * sc, y1 = x[base + N_] * sc, y2 = x[base + 2 * N_] * sc;
        y[base]          = y0;
        y[base + N_]     = y1;
        y[base + 2 * N_] = y2;
        ysp[base]          = splitpack(y0);
        ysp[base + N_]     = splitpack(y1);
        ysp[base + 2 * N_] = splitpack(y2);
    }
}

// ---------------------------------------------------------------------------
// weight split-conversion: 15 weights, one launch
// ---------------------------------------------------------------------------
struct WCArgs { const float* src[15]; u32* dst[15]; int n[15]; };
__global__ __launch_bounds__(256) void wconv_kernel(WCArgs a)
{
    const int w = blockIdx.y;
    const int i = blockIdx.x * 256 + threadIdx.x;
    if (i < a.n[w]) a.dst[w][i] = splitpack(a.src[w][i]);
}

// ---------------------------------------------------------------------------
// split bf16x2 MFMA GEMM: Y = Z + W·X computed as Wh·Xh + Wh·Xl + Wl·Xh.
// 64x64 tile, K-step 64, 4 waves (2x2 of 32x32). LDS XOR-swizzled.
// XMODE 0: X[(b*K + c)*M + m]   XMODE 1: X[((b*N+n)*3+t)*K + c], m = t*N+n
// OMODE 0: fp32 (+Z)   1: split-packed u32   2: both
// ---------------------------------------------------------------------------
template <int XMODE, int OMODE>
__device__ __forceinline__ void gemm_tile(
    const u32* __restrict__ Wsp, int wstride,
    const u32* __restrict__ Xsp, int K,
    const float* __restrict__ Z, float* __restrict__ Y, u32* __restrict__ Ysp,
    int b, int m0, int o0loc, int oglob, int Ostr,
    ush Wh[64][64], ush Wl[64][64], ush Xh[64][64], ush Xl[64][64])
{
    const int M = 3 * N_;
    const int tid = threadIdx.x;
    const int lane = tid & 63, wv = tid >> 6;
    const int col = lane & 15, grp = lane >> 4;
    const int wo = wv >> 1, wm = wv & 1;

    f32x4 acc[2][2];
    #pragma unroll
    for (int i = 0; i < 2; ++i)
        #pragma unroll
        for (int j = 0; j < 2; ++j) { f32x4 z = {0.f,0.f,0.f,0.f}; acc[i][j] = z; }

    for (int kk = 0; kk < K; kk += 64) {
        // ---- stage W tile (64 o x 64 k) ----
        {
            const int o = tid >> 2, kg = tid & 3;
            const u32* src = Wsp + (size_t)(o0loc + o) * wstride + kk + kg * 16;
            u32 buf[16];
            #pragma unroll
            for (int j = 0; j < 4; ++j) *(uint4*)&buf[j * 4] = *(const uint4*)(src + j * 4);
            short8v h0, h1, l0, l1; unpack16(buf, h0, h1, l0, l1);
            const int s0 = ((kg * 2)     ^ (o & 7)) << 3;
            const int s1 = ((kg * 2 + 1) ^ (o & 7)) << 3;
            *(short8v*)&Wh[o][s0] = h0; *(short8v*)&Wh[o][s1] = h1;
            *(short8v*)&Wl[o][s0] = l0; *(short8v*)&Wl[o][s1] = l1;
        }
        // ---- stage X tile (64 k x 64 m), stored transposed Xs[m][k] ----
        if (XMODE == 0) {
            const int m = lane, kq = wv;
            const u32* src = Xsp + ((size_t)b * K + kk + kq * 16) * M + m0 + m;
            u32 buf[16];
            #pragma unroll
            for (int j = 0; j < 16; ++j) buf[j] = src[(size_t)j * M];
            short8v h0, h1, l0, l1; unpack16(buf, h0, h1, l0, l1);
            const int s0 = ((kq * 2)     ^ (m & 7)) << 3;
            const int s1 = ((kq * 2 + 1) ^ (m & 7)) << 3;
            *(short8v*)&Xh[m][s0] = h0; *(short8v*)&Xh[m][s1] = h1;
            *(short8v*)&Xl[m][s0] = l0; *(short8v*)&Xl[m][s1] = l1;
        } else {
            const int m = tid >> 2, kg = tid & 3;
            const int mg = m0 + m;
            const int n = mg & (N_ - 1), t = mg >> 11;
            const u32* src = Xsp + ((size_t)(b * N_ + n) * 3 + t) * K + kk + kg * 16;
            u32 buf[16];
            #pragma unroll
            for (int j = 0; j < 4; ++j) *(uint4*)&buf[j * 4] = *(const uint4*)(src + j * 4);
            short8v h0, h1, l0, l1; unpack16(buf, h0, h1, l0, l1);
            const int s0 = ((kg * 2)     ^ (m & 7)) << 3;
            const int s1 = ((kg * 2 + 1) ^ (m & 7)) << 3;
            *(short8v*)&Xh[m][s0] = h0; *(short8v*)&Xh[m][s1] = h1;
            *(short8v*)&Xl[m][s0] = l0; *(short8v*)&Xl[m][s1] = l1;
        }
        __syncthreads();
        // ---- 24 MFMAs per K-step: hi*hi + hi*lo + lo*hi ----
        #pragma unroll
        for (int kc = 0; kc < 2; ++kc) {
            const int sk = ((kc * 4 + grp) ^ (col & 7)) << 3;
            short8v ah0 = *(const short8v*)&Wh[wo * 32 + col][sk];
            short8v ah1 = *(const short8v*)&Wh[wo * 32 + 16 + col][sk];
            short8v al0 = *(const short8v*)&Wl[wo * 32 + col][sk];
            short8v al1 = *(const short8v*)&Wl[wo * 32 + 16 + col][sk];
            short8v xh0 = *(const short8v*)&Xh[wm * 32 + col][sk];
            short8v xh1 = *(const short8v*)&Xh[wm * 32 + 16 + col][sk];
            short8v xl0 = *(const short8v*)&Xl[wm * 32 + col][sk];
            short8v xl1 = *(const short8v*)&Xl[wm * 32 + 16 + col][sk];
            acc[0][0] = __builtin_amdgcn_mfma_f32_16x16x32_bf16(ah0, xh0, acc[0][0], 0, 0, 0);
            acc[0][1] = __builtin_amdgcn_mfma_f32_16x16x32_bf16(ah0, xh1, acc[0][1], 0, 0, 0);
            acc[1][0] = __builtin_amdgcn_mfma_f32_16x16x32_bf16(ah1, xh0, acc[1][0], 0, 0, 0);
            acc[1][1] = __builtin_amdgcn_mfma_f32_16x16x32_bf16(ah1, xh1, acc[1][1], 0, 0, 0);
            acc[0][0] = __builtin_amdgcn_mfma_f32_16x16x32_bf16(ah0, xl0, acc[0][0], 0, 0, 0);
            acc[0][1] = __builtin_amdgcn_mfma_f32_16x16x32_bf16(ah0, xl1, acc[0][1], 0, 0, 0);
            acc[1][0] = __builtin_amdgcn_mfma_f32_16x16x32_bf16(ah1, xl0, acc[1][0], 0, 0, 0);
            acc[1][1] = __builtin_amdgcn_mfma_f32_16x16x32_bf16(ah1, xl1, acc[1][1], 0, 0, 0);
            acc[0][0] = __builtin_amdgcn_mfma_f32_16x16x32_bf16(al0, xh0, acc[0][0], 0, 0, 0);
            acc[0][1] = __builtin_amdgcn_mfma_f32_16x16x32_bf16(al0, xh1, acc[0][1], 0, 0, 0);
            acc[1][0] = __builtin_amdgcn_mfma_f32_16x16x32_bf16(al1, xh0, acc[1][0], 0, 0, 0);
            acc[1][1] = __builtin_amdgcn_mfma_f32_16x16x32_bf16(al1, xh1, acc[1][1], 0, 0, 0);
        }
        __syncthreads();
    }
    // ---- epilogue ----
    #pragma unroll
    for (int of = 0; of < 2; ++of) {
        #pragma unroll
        for (int r = 0; r < 4; ++r) {
            const int o = oglob + wo * 32 + of * 16 + grp * 4 + r;
            #pragma unroll
            for (int mf = 0; mf < 2; ++mf) {
                const size_t idx = ((size_t)b * Ostr + o) * M + m0 + wm * 32 + mf * 16 + col;
                float v = acc[of][mf][r];
                if (OMODE != 1) {
                    if (Z) v += Z[idx];
                    Y[idx] = v;
                }
                if (OMODE != 0) Ysp[idx] = splitpack(v);
            }
        }
    }
}

template <int XMODE, int OMODE>
__global__ __launch_bounds__(256) void gemm_split_kernel(
    const u32* __restrict__ Wsp, int wstride,
    const u32* __restrict__ Xsp,
    const float* __restrict__ Z,
    float* __restrict__ Y, u32* __restrict__ Ysp,
    int Ostr, int obase, int K)
{
    __shared__ __align__(16) ush Wh[64][64];
    __shared__ __align__(16) ush Wl[64][64];
    __shared__ __align__(16) ush Xh[64][64];
    __shared__ __align__(16) ush Xl[64][64];
    gemm_tile<XMODE, OMODE>(Wsp, wstride, Xsp, K, Z, Y, Ysp,
                            blockIdx.z, blockIdx.x * 64,
                            blockIdx.y * 64, obase + blockIdx.y * 64, Ostr,
                            Wh, Wl, Xh, Xl);
}

struct QKVArgs {
    const u32* W0; const u32* W1; const u32* W2;
    const u32* X0; const u32* X1; const u32* X2;
};

// fused Q/K/V projections -> Y[(b*384 + c')*M] fp32
__global__ __launch_bounds__(256) void qkv_kernel(QKVArgs A, float* __restrict__ Y)
{
    __shared__ __align__(16) ush Wh[64][64];
    __shared__ __align__(16) ush Wl[64][64];
    __shared__ __align__(16) ush Xh[64][64];
    __shared__ __align__(16) ush Xl[64][64];
    const int wi = blockIdx.y >> 1;
    const u32* W = wi == 0 ? A.W0 : (wi == 1 ? A.W1 : A.W2);
    const u32* X = wi == 0 ? A.X0 : (wi == 1 ? A.X1 : A.X2);
    gemm_tile<0, 0>(W, 128, X, 128, nullptr, Y, nullptr,
                    blockIdx.z, blockIdx.x * 64,
                    (blockIdx.y & 1) * 64, blockIdx.y * 64, 384,
                    Wh, Wl, Xh, Xl);
}

// ---------------------------------------------------------------------------
// bf16 MFMA flash attention (fp32 qkv in, split u32 out)
// ---------------------------------------------------------------------------
#define LDT 72

__global__ __launch_bounds__(256) void attn_mfma_kernel(
    const float* __restrict__ qkv, u32* __restrict__ out_sp)
{
    __shared__ __align__(16) ush Qt[64][LDT];
    __shared__ __align__(16) ush Kt[64][LDT];
    __shared__ __align__(16) ush Vs[48][LDT];
    __shared__ __align__(16) ush Pl[4][16][LDT];

    const int bh = blockIdx.y;
    const int b = bh >> 3, h = bh & 7;
    const int n0 = blockIdx.x * 64;
    const size_t hb = ((size_t)(b * 384 + h * 16)) * 3 * N_;
    const float* Q  = qkv + hb;
    const float* Kp = Q + (size_t)128 * 3 * N_;
    const float* Vp = Q + (size_t)256 * 3 * N_;
    u32* Op = out_sp + ((size_t)(b * C_ + h * 16)) * 3 * N_;

    const int tid = threadIdx.x;
    const int lane = tid & 63, wv = tid >> 6;
    const int col = lane & 15, grp = lane >> 4;

    {
        const int m = tid & 63;
        const int dq = (tid >> 6) * 4;
        #pragma unroll
        for (int p = 0; p < 3; ++p) {
            int d0 = p * 16 + dq;
            const float* src = Q + (size_t)d0 * N_ + n0 + m;
            ushort4 pk;
            pk.x = f2bf(src[0]      * 0.14433756729740643f);
            pk.y = f2bf(src[N_]     * 0.14433756729740643f);
            pk.z = f2bf(src[2 * N_] * 0.14433756729740643f);
            pk.w = f2bf(src[3 * N_] * 0.14433756729740643f);
            *(ushort4*)&Qt[m][d0] = pk;
        }
        ushort4 z4; z4.x = z4.y = z4.z = z4.w = 0;
        *(ushort4*)&Qt[m][48 + dq] = z4;
        *(ushort4*)&Kt[m][48 + dq] = z4;
    }
    __syncthreads();
    short8v qf0 = *(const short8v*)&Qt[wv * 16 + col][grp * 8];
    short8v qf1 = *(const short8v*)&Qt[wv * 16 + col][32 + grp * 8];

    f32x4 acc[3];
    #pragma unroll
    for (int db = 0; db < 3; ++db) { f32x4 z = {0.f, 0.f, 0.f, 0.f}; acc[db] = z; }
    float m_i = -1e30f, l_i = 0.f;

    for (int mt = 0; mt < N_ / 64; ++mt) {
        const int m0 = mt * 64;
        __syncthreads();
        {
            const int m = tid & 63;
            const int dq = (tid >> 6) * 4;
            #pragma unroll
            for (int p = 0; p < 3; ++p) {
                int d0 = p * 16 + dq;
                const float* src = Kp + (size_t)d0 * N_ + m0 + m;
                ushort4 pk;
                pk.x = f2bf(src[0]);
                pk.y = f2bf(src[N_]);
                pk.z = f2bf(src[2 * N_]);
                pk.w = f2bf(src[3 * N_]);
                *(ushort4*)&Kt[m][d0] = pk;
            }
        }
        {
            const int m2 = (tid & 31) * 2;
            const int dr = tid >> 5;
            #pragma unroll
            for (int p = 0; p < 6; ++p) {
                int d = p * 8 + dr;
                float2 v2 = *(const float2*)&Vp[(size_t)d * N_ + m0 + m2];
                ushort2 pk;
                pk.x = f2bf(v2.x);
                pk.y = f2bf(v2.y);
                *(ushort2*)&Vs[d][m2] = pk;
            }
        }
        __syncthreads();

        f32x4 sf[4];
        #pragma unroll
        for (int kb = 0; kb < 4; ++kb) {
            short8v ka0 = *(const short8v*)&Kt[kb * 16 + col][grp * 8];
            short8v ka1 = *(const short8v*)&Kt[kb * 16 + col][32 + grp * 8];
            f32x4 z = {0.f, 0.f, 0.f, 0.f};
            z = __builtin_amdgcn_mfma_f32_16x16x32_bf16(ka0, qf0, z, 0, 0, 0);
            z = __builtin_amdgcn_mfma_f32_16x16x32_bf16(ka1, qf1, z, 0, 0, 0);
            sf[kb] = z;
        }

        float pmax = -1e30f;
        #pragma unroll
        for (int kb = 0; kb < 4; ++kb)
            #pragma unroll
            for (int r = 0; r < 4; ++r) pmax = fmaxf(pmax, sf[kb][r]);
        pmax = fmaxf(pmax, __shfl_xor(pmax, 16, 64));
        pmax = fmaxf(pmax, __shfl_xor(pmax, 32, 64));
        float mnew = fmaxf(m_i, pmax);
        float sc_old = __expf(m_i - mnew);
        float psum = 0.f;
        #pragma unroll
        for (int kb = 0; kb < 4; ++kb) {
            float e0 = __expf(sf[kb][0] - mnew);
            float e1 = __expf(sf[kb][1] - mnew);
            float e2 = __expf(sf[kb][2] - mnew);
            float e3 = __expf(sf[kb][3] - mnew);
            psum += e0 + e1 + e2 + e3;
            ushort4 pk;
            pk.x = f2bf(e0); pk.y = f2bf(e1); pk.z = f2bf(e2); pk.w = f2bf(e3);
            *(ushort4*)&Pl[wv][col][kb * 16 + grp * 4] = pk;
        }
        psum += __shfl_xor(psum, 16, 64);
        psum += __shfl_xor(psum, 32, 64);
        l_i = l_i * sc_old + psum;
        m_i = mnew;
        #pragma unroll
        for (int db = 0; db < 3; ++db) {
            acc[db][0] *= sc_old; acc[db][1] *= sc_old;
            acc[db][2] *= sc_old; acc[db][3] *= sc_old;
        }

        #pragma unroll
        for (int hh = 0; hh < 2; ++hh) {
            short8v pf = *(const short8v*)&Pl[wv][col][hh * 32 + grp * 8];
            #pragma unroll
            for (int db = 0; db < 3; ++db) {
                short8v vf = *(const short8v*)&Vs[db * 16 + col][hh * 32 + grp * 8];
                acc[db] = __builtin_amdgcn_mfma_f32_16x16x32_bf16(vf, pf, acc[db], 0, 0, 0);
            }
        }
    }

    const float inv = 1.f / l_i;
    #pragma unroll
    for (int db = 0; db < 3; ++db)
        #pragma unroll
        for (int r = 0; r < 4; ++r) {
            int d = db * 16 + grp * 4 + r;
            Op[(size_t)d * N_ + n0 + wv * 16 + col] = splitpack(acc[db][r] * inv);
        }
}

// ---------------------------------------------------------------------------
// transpose (B,C,3,N) -> (B,N,3,C) fp32
// ---------------------------------------------------------------------------
__global__ __launch_bounds__(256) void transpose_kernel(const float* __restrict__ x,
                                                        float* __restrict__ y)
{
    __shared__ float tile[32][33];
    const int z = blockIdx.z;
    const int b = z / 3, t = z % 3;
    const int n0 = blockIdx.x * 32, c0 = blockIdx.y * 32;
    const int tx = threadIdx.x & 31, ty = threadIdx.x >> 5;
    #pragma unroll
    for (int p = 0; p < 4; ++p) {
        int c = c0 + ty + p * 8;
        tile[ty + p * 8][tx] = x[((size_t)(b * C_ + c) * 3 + t) * N_ + n0 + tx];
    }
    __syncthreads();
    #pragma unroll
    for (int p = 0; p < 4; ++p) {
        int n = n0 + ty + p * 8;
        y[((size_t)(b * N_ + n) * 3 + t) * C_ + c0 + tx] = tile[tx][ty + p * 8];
    }
}

// ---------------------------------------------------------------------------
// graph attention: fp32 in, split u32 edge buffer out
// ---------------------------------------------------------------------------
__global__ __launch_bounds__(256) void graph_kernel(
    const float* __restrict__ tq, const float* __restrict__ tv,
    const int* __restrict__ idx, u32* __restrict__ g)
{
    __shared__ float center[384];
    __shared__ float sd[16];
    __shared__ int nbr_i[16];
    const int b = blockIdx.y, n = blockIdx.x;
    const int tid = threadIdx.x;
    const float* qrow = tq + (size_t)(b * N_ + n) * 384;
    for (int e = tid; e < 384; e += 256) center[e] = qrow[e];
    if (tid < 16) nbr_i[tid] = idx[(size_t)(b * N_ + n) * 16 + tid];
    __syncthreads();

    const int lane = tid & 63, wv = tid >> 6;
    for (int kk = 0; kk < 4; ++kk) {
        int k = wv * 4 + kk;
        const float* vrow = tv + ((size_t)b * N_ + nbr_i[k]) * 384;
        float p = 0.f;
        #pragma unroll
        for (int jj = 0; jj < 6; ++jj) {
            int e = lane + jj * 64;
            p += center[e] * vrow[e];
        }
        #pragma unroll
        for (int off = 32; off; off >>= 1) p += __shfl_down(p, off, 64);
        if (lane == 0) sd[k] = p * 0.05103103630798288f;
    }
    __syncthreads();

    float mx = -1e30f;
    #pragma unroll
    for (int k = 0; k < 16; ++k) mx = fmaxf(mx, sd[k]);
    float a[16]; float ssum = 0.f;
    #pragma unroll
    for (int k = 0; k < 16; ++k) { a[k] = __expf(sd[k] - mx); ssum += a[k]; }
    float inv = 1.f / ssum;

    for (int e = tid; e < 384; e += 256) {
        float accv = 0.f;
        #pragma unroll
        for (int k = 0; k < 16; ++k)
            accv += a[k] * tv[((size_t)b * N_ + nbr_i[k]) * 384 + e];
        accv *= inv;
        float ce = center[e];
        int t = e >> 7, c = e & 127;
        size_t gb = ((size_t)(b * N_ + n) * 3 + t) * 256;
        g[gb + c]       = splitpack(accv - ce);
        g[gb + 128 + c] = splitpack(ce);
    }
}

// ---------------------------------------------------------------------------
// vn_leaky: fp32 x,d in -> split u32 out
// ---------------------------------------------------------------------------
__global__ __launch_bounds__(256) void leaky_kernel(const float* __restrict__ x,
                                                    const float* __restrict__ d,
                                                    u32* __restrict__ y)
{
    size_t p = (size_t)blockIdx.x * 256 + threadIdx.x;
    size_t bh = p / N_, n = p % N_;
    size_t base = bh * 3 * N_ + n;
    float x0 = x[base], x1 = x[base + N_], x2 = x[base + 2 * N_];
    float d0 = d[base], d1 = d[base + N_], d2 = d[base + 2 * N_];
    float dot = x0 * d0 + x1 * d1 + x2 * d2;
    float dsq = d0 * d0 + d1 * d1 + d2 * d2;
    float f = dot / (dsq + EPS_);
    bool pos = dot >= 0.f;
    float y0 = pos ? x0 : x0 - f * d0;
    float y1 = pos ? x1 : x1 - f * d1;
    float y2 = pos ? x2 : x2 - f * d2;
    y[base]          = splitpack(NS_ * x0 + (1.f - NS_) * y0);
    y[base + N_]     = splitpack(NS_ * x1 + (1.f - NS_) * y1);
    y[base + 2 * N_] = splitpack(NS_ * x2 + (1.f - NS_) * y2);
}

// ---------------------------------------------------------------------------
extern "C" void kernel_launch(void* const* d_in, const int* in_sizes, int n_in,
                              void* d_out, int out_size, void* d_ws, size_t ws_size,
                              hipStream_t stream)
{
    const float* q_in = (const float*)d_in[0];
    const float* v_in = (const float*)d_in[1];
    const int*   idx_s = (const int*)d_in[4];
    const int*   idx_c = (const int*)d_in[5];
    const float* g1 = (const float*)d_in[6];
    const float* b1 = (const float*)d_in[7];
    const float* g2 = (const float*)d_in[8];
    const float* b2 = (const float*)d_in[9];
    const float* gq = (const float*)d_in[10];
    const float* bq = (const float*)d_in[11];
    const float* gv = (const float*)d_in[12];
    const float* bv = (const float*)d_in[13];
    float* out = (float*)d_out;
    float* ws  = (float*)d_ws;

    const size_t S1 = (size_t)B_ * C_ * 3 * N_; // 1572864 elems
    // slot map (phase A/B):           (phase C aliases):
    float* nx    = ws;                 // 0      (clobbered by hd)
    float* nv    = ws + S1;            // 1
    u32*   nx_s  = (u32*)(ws + 2*S1);  // 2
    u32*   nv_s  = (u32*)(ws + 3*S1);  // 3
    float* qkv   = ws + 4*S1;          // 4-6
    u32*   ao_s  = (u32*)(ws + 7*S1);  // 7
    u32*   f12_s = (u32*)(ws + 8*S1);  // 8-9
    u32*   gbuf_s= (u32*)(ws + 10*S1); // 10-11
    float* qa    = ws + 12*S1;         // 12
    float* qb    = ws + 13*S1;         // 13
    float* t1    = ws + 14*S1;         // 14
    float* t2    = ws + 15*S1;         // 15
    u32*   wsp   = (u32*)(ws + 16*S1); // 16 (655360 u32 used)
    // phase C:
    float* hd    = ws;                 // 0-3   (after nx_s consumed)
    float* h1    = ws + 4*S1;          // 4-7
    u32*   h1_s  = (u32*)(ws + 8*S1);  // 8-11  (reused as leaky out)

    // weight split-plane offsets inside wsp
    const int wn[15]  = {16384,16384,16384,16384,32768,32768,
                         16384,16384,16384,16384,32768,32768,
                         65536,262144,65536};
    u32* wd[15];
    {
        int off = 0;
        for (int i = 0; i < 15; ++i) { wd[i] = wsp + off; off += wn[i]; }
    }
    u32 *Wq_s = wd[0], *Wk_s = wd[1], *Wv_s = wd[2], *Wo_s = wd[3], *We_s = wd[4], *Wm_s = wd[5];
    u32 *Wq_c = wd[6], *Wk_c = wd[7], *Wv_c = wd[8], *Wo_c = wd[9], *We_c = wd[10], *Wm_c = wd[11];
    u32 *W1 = wd[12], *Dact = wd[13], *W2 = wd[14];

    {
        WCArgs a;
        for (int i = 0; i < 15; ++i) {
            a.src[i] = (const float*)d_in[14 + i];
            a.dst[i] = wd[i];
            a.n[i]   = wn[i];
        }
        wconv_kernel<<<dim3(1024, 15), 256, 0, stream>>>(a);
    }

    dim3 gln(N_ / 32, B_);
    dim3 gtr(N_ / 32, C_ / 32, B_ * 3);
    dim3 gat(N_ / 64, B_ * HEADS_);
    dim3 ggr(N_, B_);
    dim3 gqkv(96, 6, B_);
    dim3 gg128(96, 2, B_);
    dim3 gg512(96, 8, B_);

    // ---- Phase A: self attention block ----
    ln_kernel<<<gln, 256, 0, stream>>>(q_in, g1, b1, nx, nx_s);
    {
        QKVArgs A{Wq_s, Wk_s, Wv_s, nx_s, nx_s, nx_s};
        qkv_kernel<<<gqkv, 256, 0, stream>>>(A, qkv);
    }
    transpose_kernel<<<gtr, 256, 0, stream>>>(nx, t1);
    attn_mfma_kernel<<<gat, 256, 0, stream>>>(qkv, ao_s);
    gemm_split_kernel<0,1><<<gg128, 256, 0, stream>>>(Wo_s, 128, ao_s, nullptr, nullptr, f12_s, 256, 0, 128);
    graph_kernel<<<ggr, 256, 0, stream>>>(t1, t1, idx_s, gbuf_s);
    gemm_split_kernel<1,1><<<gg128, 256, 0, stream>>>(We_s, 256, gbuf_s, nullptr, nullptr, f12_s, 256, 128, 256);
    gemm_split_kernel<0,0><<<gg128, 256, 0, stream>>>(Wm_s, 256, f12_s, q_in, qa, nullptr, 128, 0, 256);

    // ---- Phase B: cross attention block ----
    ln_kernel<<<gln, 256, 0, stream>>>(qa,   gq, bq, nx, nx_s);
    ln_kernel<<<gln, 256, 0, stream>>>(v_in, gv, bv, nv, nv_s);
    {
        QKVArgs A{Wq_c, Wk_c, Wv_c, nx_s, nv_s, nv_s};
        qkv_kernel<<<gqkv, 256, 0, stream>>>(A, qkv);
    }
    transpose_kernel<<<gtr, 256, 0, stream>>>(nx, t1);
    transpose_kernel<<<gtr, 256, 0, stream>>>(nv, t2);
    attn_mfma_kernel<<<gat, 256, 0, stream>>>(qkv, ao_s);
    gemm_split_kernel<0,1><<<gg128, 256, 0, stream>>>(Wo_c, 128, ao_s, nullptr, nullptr, f12_s, 256, 0, 128);
    graph_kernel<<<ggr, 256, 0, stream>>>(t1, t2, idx_c, gbuf_s);
    gemm_split_kernel<1,1><<<gg128, 256, 0, stream>>>(We_c, 256, gbuf_s, nullptr, nullptr, f12_s, 256, 128, 256);
    gemm_split_kernel<0,0><<<gg128, 256, 0, stream>>>(Wm_c, 256, f12_s, qa, qb, nullptr, 128, 0, 256);

    // ---- Phase C: vector MLP ----
    ln_kernel<<<gln, 256, 0, stream>>>(qb, g2, b2, nx, nx_s);
    gemm_split_kernel<0,2><<<gg512, 256, 0, stream>>>(W1, 128, nx_s, nullptr, h1, h1_s, 512, 0, 128);
    gemm_split_kernel<0,0><<<gg512, 256, 0, stream>>>(Dact, 512, h1_s, nullptr, hd, nullptr, 512, 0, 512);
    leaky_kernel<<<dim3((B_ * HID_ * N_) / 256), 256, 0, stream>>>(h1, hd, h1_s);
    gemm_split_kernel<0,0><<<gg128, 256, 0, stream>>>(W2, 512, h1_s, qb, out, nullptr, 128, 0, 512);
}